// Round 1
// baseline (86.487 us; speedup 1.0000x reference)
//
#include <hip/hip_runtime.h>

#define BLK 256
#define GRID_Y 16

// ws layout: [0..7] double rank_sum, [8..15] double reg_sum, [16..23] ull cnt
__global__ __launch_bounds__(BLK) void svm_partial(const float* __restrict__ pred,
                                                   const float* __restrict__ target,
                                                   double* __restrict__ ws_sums,
                                                   unsigned long long* __restrict__ ws_cnt,
                                                   int n) {
    __shared__ float sh_p[BLK];
    __shared__ float sh_t[BLK];
    __shared__ float red_rank[BLK / 64];
    __shared__ float red_reg[BLK / 64];
    __shared__ unsigned int red_cnt[BLK / 64];

    const int tid = threadIdx.x;
    const int i = blockIdx.x * BLK + tid;

    const float p_i = pred[i];
    const float t_i = target[2 * i];
    const float e_i = target[2 * i + 1];
    const bool active = (e_i == 1.0f);
    const float pi1 = 1.0f + p_i;   // hinge = max(pi1 - p_j, 0)

    float rank_acc = 0.0f;
    unsigned int cnt_acc = 0u;

    const int jchunk = n / GRID_Y;
    const int j0 = blockIdx.y * jchunk;
    const int j1 = j0 + jchunk;

    for (int jt = j0; jt < j1; jt += BLK) {
        __syncthreads();
        sh_p[tid] = pred[jt + tid];
        sh_t[tid] = target[2 * (jt + tid)];
        __syncthreads();
        if (active) {
            #pragma unroll 8
            for (int jj = 0; jj < BLK; ++jj) {
                float tj = sh_t[jj];              // broadcast LDS read (free)
                float h = pi1 - sh_p[jj];
                h = fmaxf(h, 0.0f);
                bool m = tj > t_i;
                rank_acc += m ? h * h : 0.0f;
                cnt_acc += m ? 1u : 0u;
            }
        }
    }

    // regression term: count each i exactly once (only the y==0 slice)
    float reg_acc = 0.0f;
    if (blockIdx.y == 0) {
        float diff = p_i - t_i;
        if (e_i == 0.0f) diff = fmaxf(diff, 0.0f);
        reg_acc = diff * diff;
    }

    // wave (64-lane) shuffle reduction
    #pragma unroll
    for (int off = 32; off > 0; off >>= 1) {
        rank_acc += __shfl_down(rank_acc, off);
        reg_acc  += __shfl_down(reg_acc, off);
        cnt_acc  += __shfl_down(cnt_acc, off);
    }

    const int wave = tid >> 6;
    const int lane = tid & 63;
    if (lane == 0) {
        red_rank[wave] = rank_acc;
        red_reg[wave]  = reg_acc;
        red_cnt[wave]  = cnt_acc;
    }
    __syncthreads();

    if (tid == 0) {
        float r = 0.0f, g = 0.0f;
        unsigned int c = 0u;
        #pragma unroll
        for (int w = 0; w < BLK / 64; ++w) {
            r += red_rank[w];
            g += red_reg[w];
            c += red_cnt[w];
        }
        atomicAdd(&ws_sums[0], (double)r);
        atomicAdd(&ws_sums[1], (double)g);
        atomicAdd(ws_cnt, (unsigned long long)c);
    }
}

__global__ void svm_finalize(const double* __restrict__ ws_sums,
                             const unsigned long long* __restrict__ ws_cnt,
                             float* __restrict__ out, int n) {
    double rank = ws_sums[0];
    double reg = ws_sums[1];
    unsigned long long c = *ws_cnt;
    double cnt = (double)(c > 0ull ? c : 1ull);
    out[0] = (float)(0.5 * rank / cnt + 0.5 * reg / (double)n);
}

extern "C" void kernel_launch(void* const* d_in, const int* in_sizes, int n_in,
                              void* d_out, int out_size, void* d_ws, size_t ws_size,
                              hipStream_t stream) {
    const float* pred = (const float*)d_in[0];
    const float* target = (const float*)d_in[1];
    float* out = (float*)d_out;
    const int n = in_sizes[0];  // 8192

    double* ws_sums = (double*)d_ws;
    unsigned long long* ws_cnt = (unsigned long long*)((char*)d_ws + 16);

    hipMemsetAsync(d_ws, 0, 32, stream);

    dim3 grid(n / BLK, GRID_Y);
    svm_partial<<<grid, BLK, 0, stream>>>(pred, target, ws_sums, ws_cnt, n);
    svm_finalize<<<1, 1, 0, stream>>>(ws_sums, ws_cnt, out, n);
}